// Round 1
// baseline (3745.589 us; speedup 1.0000x reference)
//
#include <hip/hip_runtime.h>
#include <math.h>

namespace {
constexpr int kH    = 256;   // hidden
constexpr int kM    = 32;    // stack value dim
constexpr int kIn   = 131;   // input dim
constexpr int kOut  = 131;   // output dim
constexpr int kB    = 32;    // batch
constexpr int kTenc = 128;   // encoder steps (X[:-1])
constexpr int kT    = 256;   // total sequential steps
constexpr int kCap  = 257;   // stack capacity
constexpr int kG    = 1024;  // 4*H gates
}

__device__ __forceinline__ float sigf(float x){ return 1.0f/(1.0f+expf(-x)); }

// dst[c*R + r] = src[r*stride + col0 + c]   (dst layout [C][R])
__global__ void k_transpose(float* __restrict__ dst, const float* __restrict__ src,
                            int R, int C, int stride, int col0){
  int idx = blockIdx.x*256 + threadIdx.x;
  if (idx >= R*C) return;
  int rr = idx / C;
  int cc = idx - rr*C;
  dst[cc*R + rr] = src[rr*stride + col0 + cc];
}

// gatesX[t][b][col] = sum_k x_t[b][k]*Wih[col][k] + bih[col] + bhh[col]
__global__ void k_gatesx(const float* __restrict__ X, const float* __restrict__ Y,
                         const float* __restrict__ WixT_e, const float* __restrict__ WixT_d,
                         const float* __restrict__ bih_e, const float* __restrict__ bhh_e,
                         const float* __restrict__ bih_d, const float* __restrict__ bhh_d,
                         float* __restrict__ gatesX){
  const int t   = blockIdx.x;                    // 0..255
  const int col = blockIdx.y*256 + threadIdx.x;  // 0..1023
  __shared__ float xl[kB*kIn];
  const float* xsrc;
  if (t < kTenc)       xsrc = X + (size_t)t*kB*kIn;          // encoder: X[t]
  else if (t == kTenc) xsrc = X + (size_t)kTenc*kB*kIn;      // decoder step0: X[-1]
  else                 xsrc = Y + (size_t)(t-kTenc-1)*kB*kIn;// decoder: Y[t-129]
  for (int i = threadIdx.x; i < kB*kIn; i += 256) xl[i] = xsrc[i];
  __syncthreads();
  const float* WT   = (t < kTenc) ? WixT_e : WixT_d;
  const float  bias = (t < kTenc) ? (bih_e[col] + bhh_e[col]) : (bih_d[col] + bhh_d[col]);
  float acc[kB];
#pragma unroll
  for (int b = 0; b < kB; ++b) acc[b] = bias;
  for (int k = 0; k < kIn; ++k){
    float wk = WT[k*kG + col];
#pragma unroll
    for (int b = 0; b < kB; ++b) acc[b] += wk * xl[b*kIn + k];
  }
  float* outp = gatesX + (size_t)t*kB*kG + col;
#pragma unroll
  for (int b = 0; b < kB; ++b) outp[(size_t)b*kG] = acc[b];
}

// inclusive suffix sum across a 64-lane wave: result[l] = sum_{l' >= l} x[l']
__device__ __forceinline__ float wave_suffix_incl(float x, int lane){
#pragma unroll
  for (int off = 1; off < 64; off <<= 1){
    float t = __shfl_down(x, off);
    if (lane + off < 64) x += t;
  }
  return x;
}

__global__ void __launch_bounds__(1024)
k_seq(const float* __restrict__ gatesX,
      const float* __restrict__ WhhT_e, const float* __restrict__ WhhT_d,
      const float* __restrict__ WirT_e, const float* __restrict__ WirT_d,
      const float* __restrict__ Wd, const float* __restrict__ bd,
      const float* __restrict__ Wu, const float* __restrict__ bu,
      const float* __restrict__ Wv, const float* __restrict__ bv,
      const float* __restrict__ h0, const float* __restrict__ c0,
      float* __restrict__ Hdec){
  const int b    = blockIdx.x;     // one batch element per block
  const int tid  = threadIdx.x;
  const int lane = tid & 63;
  const int wave = tid >> 6;

  __shared__ float h[kH], c[kH], r[kM], v[kM];
  __shared__ float gl[kG];
  __shared__ float sbuf[kCap];
  __shared__ float coeff[kCap];
  __shared__ float Vbuf[kCap*kM];
  __shared__ float red[1024];
  __shared__ float du[2];

  if (tid < kH){ h[tid] = h0[tid]; c[tid] = c0[tid]; }
  if (tid < kM) r[tid] = 0.f;
  for (int i = tid; i < kCap; i += 1024) sbuf[i] = 0.f;
  for (int i = tid; i < kCap*kM; i += 1024) Vbuf[i] = 0.f;
  __syncthreads();

  for (int t = 0; t < kT; ++t){
    const float* WhhT = (t < kTenc) ? WhhT_e : WhhT_d;
    const float* WirT = (t < kTenc) ? WirT_e : WirT_d;

    // ---- phase 1: gates = gatesX[t] + h@Whh^T + r@Wih_r^T (thread = one gate col)
    float a0 = gatesX[((size_t)t*kB + b)*kG + tid];
    float a1 = 0.f, a2 = 0.f, a3 = 0.f;
#pragma unroll 2
    for (int k = 0; k < kH; k += 4){
      a0 += h[k+0]*WhhT[(size_t)(k+0)*kG + tid];
      a1 += h[k+1]*WhhT[(size_t)(k+1)*kG + tid];
      a2 += h[k+2]*WhhT[(size_t)(k+2)*kG + tid];
      a3 += h[k+3]*WhhT[(size_t)(k+3)*kG + tid];
    }
#pragma unroll
    for (int k = 0; k < kM; k += 4){
      a0 += r[k+0]*WirT[(size_t)(k+0)*kG + tid];
      a1 += r[k+1]*WirT[(size_t)(k+1)*kG + tid];
      a2 += r[k+2]*WirT[(size_t)(k+2)*kG + tid];
      a3 += r[k+3]*WirT[(size_t)(k+3)*kG + tid];
    }
    gl[tid] = (a0+a1) + (a2+a3);
    __syncthreads();

    // ---- phase 2: LSTM cell (gate order i,f,g,o)
    if (tid < kH){
      float ig = sigf(gl[tid]);
      float fg = sigf(gl[kH + tid]);
      float gg = tanhf(gl[2*kH + tid]);
      float og = sigf(gl[3*kH + tid]);
      float cn = fg*c[tid] + ig*gg;
      c[tid] = cn;
      float hn = og*tanhf(cn);
      h[tid] = hn;
      if (t >= kTenc) Hdec[((size_t)(t-kTenc)*kB + b)*kH + tid] = hn;
    }
    __syncthreads();

    // ---- phase 3: controller d,u (waves 0,1), v (threads 256..511, 8 lanes/output)
    if (wave == 0){
      float p = 0.f;
      for (int k = lane; k < kH; k += 64) p += h[k]*Wd[k];
#pragma unroll
      for (int off = 32; off; off >>= 1) p += __shfl_down(p, off);
      if (lane == 0) du[0] = sigf(p + bd[0]);
    } else if (wave == 1){
      float p = 0.f;
      for (int k = lane; k < kH; k += 64) p += h[k]*Wu[k];
#pragma unroll
      for (int off = 32; off; off >>= 1) p += __shfl_down(p, off);
      if (lane == 0) du[1] = sigf(p + bu[0]);
    } else if (tid >= 256 && tid < 512){
      int m = (tid - 256) >> 3;
      int l = tid & 7;
      float p = 0.f;
      for (int k = l; k < kH; k += 8) p += h[k]*Wv[m*kH + k];
#pragma unroll
      for (int off = 4; off; off >>= 1){
        float tv = __shfl_down(p, off);
        if (l + off < 8) p += tv;
      }
      if (l == 0) v[m] = tanhf(p + bv[m]);
    }
    __syncthreads();

    // ---- phase 4: neural-stack update, wave 0 only (shuffle-based suffix scans)
    const int cnt = t + 1;   // reference cnt starts at 1
    if (wave == 0){
      if (lane < kM) Vbuf[cnt*kM + lane] = v[lane];
      const float dd = du[0], uu = du[1];
      float sm[5], sn[5];
      float csum = 0.f;
#pragma unroll
      for (int q = 0; q < 5; ++q){             // lane owns indices lane*5+q
        int i = lane*5 + q;
        float s = (i < cnt) ? sbuf[i] : 0.f;   // masked strengths s_m
        sm[q] = s; csum += s;
      }
      float run = wave_suffix_incl(csum, lane) - csum;  // sum of s_m above my chunk
      float csum2 = 0.f;
#pragma unroll
      for (int q = 4; q >= 0; --q){            // high->low: run == totprev[i]
        int i = lane*5 + q;
        float s;
        if (i == cnt)      s = dd;                                   // push
        else if (i < cnt)  s = fmaxf(sm[q] - fmaxf(uu - run, 0.f), 0.f); // pop u
        else               s = 0.f;
        sn[q] = s;
        run  += sm[q];
        csum2 += s;
      }
#pragma unroll
      for (int q = 0; q < 5; ++q){
        int i = lane*5 + q;
        if (i < kCap) sbuf[i] = sn[q];
      }
      float run2 = wave_suffix_incl(csum2, lane) - csum2;
#pragma unroll
      for (int q = 4; q >= 0; --q){            // run2 == tots[i]
        int i = lane*5 + q;
        float cf = fminf(sn[q], fmaxf(1.f - run2, 0.f));
        if (i < kCap) coeff[i] = cf;
        run2 += sn[q];
      }
    }
    __syncthreads();

    // ---- phase 5: r[m] = sum_i coeff[i]*Vbuf[i][m]
    {
      int m = tid & 31, grp = tid >> 5;
      float p = 0.f;
      for (int i = grp; i <= cnt; i += 32) p += coeff[i]*Vbuf[i*kM + m];
      red[tid] = p;
    }
    __syncthreads();
    if (tid < kM){
      float s = 0.f;
#pragma unroll
      for (int g2 = 0; g2 < 32; ++g2) s += red[g2*32 + tid];
      r[tid] = s;
    }
    __syncthreads();
  }
}

// oc = tanh(h@Wo^T + bo); out = log_softmax(oc@Wlin^T + blin)
__global__ void k_out(const float* __restrict__ Hdec,
                      const float* __restrict__ WoT, const float* __restrict__ bo,
                      const float* __restrict__ WlinT, const float* __restrict__ blin,
                      float* __restrict__ out){
  const int row = blockIdx.x;    // t*32 + b
  const int tid = threadIdx.x;   // 256
  __shared__ float hr[kH], oc[kH], lg[kOut], st[2];
  hr[tid] = Hdec[(size_t)row*kH + tid];
  __syncthreads();
  float a = bo[tid];
  for (int k = 0; k < kH; ++k) a += hr[k]*WoT[k*kH + tid];
  oc[tid] = tanhf(a);
  __syncthreads();
  if (tid < kOut){
    float a2 = blin[tid];
    for (int k = 0; k < kH; ++k) a2 += oc[k]*WlinT[k*kOut + tid];
    lg[tid] = a2;
  }
  __syncthreads();
  if (tid < 64){
    float mx = -3.4e38f;
    for (int i = tid; i < kOut; i += 64) mx = fmaxf(mx, lg[i]);
#pragma unroll
    for (int off = 32; off; off >>= 1) mx = fmaxf(mx, __shfl_down(mx, off));
    mx = __shfl(mx, 0);
    float se = 0.f;
    for (int i = tid; i < kOut; i += 64) se += expf(lg[i] - mx);
#pragma unroll
    for (int off = 32; off; off >>= 1) se += __shfl_down(se, off);
    if (tid == 0){ st[0] = mx; st[1] = logf(se); }
  }
  __syncthreads();
  if (tid < kOut) out[(size_t)row*kOut + tid] = lg[tid] - st[0] - st[1];
}

extern "C" void kernel_launch(void* const* d_in, const int* in_sizes, int n_in,
                              void* d_out, int out_size, void* d_ws, size_t ws_size,
                              hipStream_t stream){
  (void)in_sizes; (void)n_in; (void)out_size; (void)ws_size;
  const float* X     = (const float*)d_in[0];
  const float* Y     = (const float*)d_in[1];
  const float* Wih_e = (const float*)d_in[2];
  const float* Whh_e = (const float*)d_in[3];
  const float* bih_e = (const float*)d_in[4];
  const float* bhh_e = (const float*)d_in[5];
  const float* Wih_d = (const float*)d_in[6];
  const float* Whh_d = (const float*)d_in[7];
  const float* bih_d = (const float*)d_in[8];
  const float* bhh_d = (const float*)d_in[9];
  const float* Wd    = (const float*)d_in[10];
  const float* bd    = (const float*)d_in[11];
  const float* Wu    = (const float*)d_in[12];
  const float* bu    = (const float*)d_in[13];
  const float* Wv    = (const float*)d_in[14];
  const float* bv    = (const float*)d_in[15];
  const float* Wo    = (const float*)d_in[16];
  const float* bo    = (const float*)d_in[17];
  const float* Wlin  = (const float*)d_in[18];
  const float* blin  = (const float*)d_in[19];
  const float* h0    = (const float*)d_in[20];
  const float* c0    = (const float*)d_in[21];
  float* out = (float*)d_out;

  // workspace layout (floats); total ~10.4M floats ~= 41.6 MB
  float* ws = (float*)d_ws;
  size_t o = 0;
  float* gatesX = ws + o; o += (size_t)kT*kB*kG;   // 8,388,608
  float* WhhT_e = ws + o; o += (size_t)kH*kG;
  float* WhhT_d = ws + o; o += (size_t)kH*kG;
  float* WirT_e = ws + o; o += (size_t)kM*kG;
  float* WirT_d = ws + o; o += (size_t)kM*kG;
  float* WixT_e = ws + o; o += (size_t)kIn*kG;
  float* WixT_d = ws + o; o += (size_t)kIn*kG;
  float* WoT    = ws + o; o += (size_t)kH*kH;
  float* WlinT  = ws + o; o += (size_t)kH*kOut;
  float* Hdec   = ws + o; o += (size_t)128*kB*kH;

  auto tr = [&](float* dst, const float* src, int R, int C, int stride, int col0){
    int n = R*C;
    k_transpose<<<(n+255)/256, 256, 0, stream>>>(dst, src, R, C, stride, col0);
  };
  tr(WhhT_e, Whh_e, kG, kH, kH, 0);          // [256][1024]
  tr(WhhT_d, Whh_d, kG, kH, kH, 0);
  tr(WirT_e, Wih_e, kG, kM, kIn+kM, kIn);    // r-columns of Wih
  tr(WirT_d, Wih_d, kG, kM, kIn+kM, kIn);
  tr(WixT_e, Wih_e, kG, kIn, kIn+kM, 0);     // x-columns of Wih
  tr(WixT_d, Wih_d, kG, kIn, kIn+kM, 0);
  tr(WoT,   Wo,   kH,  kH, kH, 0);           // [256][256]
  tr(WlinT, Wlin, kOut, kH, kH, 0);          // [256][131]

  k_gatesx<<<dim3(kT,4), 256, 0, stream>>>(X, Y, WixT_e, WixT_d,
                                           bih_e, bhh_e, bih_d, bhh_d, gatesX);
  k_seq<<<kB, 1024, 0, stream>>>(gatesX, WhhT_e, WhhT_d, WirT_e, WirT_d,
                                 Wd, bd, Wu, bu, Wv, bv, h0, c0, Hdec);
  k_out<<<128*kB, 256, 0, stream>>>(Hdec, WoT, bo, WlinT, blin, out);
}